// Round 2
// baseline (377.385 us; speedup 1.0000x reference)
//
#include <hip/hip_runtime.h>

#define NEG_SLOPE 0.2f

__device__ __forceinline__ float leaky(float v) { return v > 0.f ? v : NEG_SLOPE * v; }
__device__ __forceinline__ float relu_f(float v) { return v > 0.f ? v : 0.f; }

// Thread layout:
//   GAT phase : pair = tid>>1 (sample within block), g = tid&1 (0=agent graph, 1=objective graph)
//   MLP phase : s = tid&127 (sample within block), half = tid>>7 (hidden units 0..63 / 64..127)
// LDS: 128 rows x 33 dwords (pad to kill bank conflicts), reused for h-exchange then o-partials.
__global__ __launch_bounds__(256, 4) void scl_fused_kernel(
    const float* __restrict__ agent_pos, const float* __restrict__ agent_vel,
    const float* __restrict__ rel_lm, const float* __restrict__ other_pos,
    const float* __restrict__ lm_pos,
    const float* __restrict__ Wl, const float* __restrict__ bl,
    const float* __restrict__ Wr, const float* __restrict__ br,
    const float* __restrict__ We, const float* __restrict__ att,
    const float* __restrict__ bias,
    const float* __restrict__ W1, const float* __restrict__ b1,
    const float* __restrict__ W2, const float* __restrict__ b2,
    float* __restrict__ out, int Btot)
{
    __shared__ float lds[128 * 33];

    const int tid  = threadIdx.x;
    const int pair = tid >> 1;
    const int g    = tid & 1;
    int b = blockIdx.x * 128 + pair;
    if (b >= Btot) b = Btot - 1;           // clamp reads; barriers stay uniform

    const int o0[3] = {1, 0, 0};
    const int o1[3] = {2, 2, 1};

    // ---- positions ----
    float px[3], py[3];
    if (g == 0) {
#pragma unroll
        for (int j = 0; j < 3; ++j) {
            px[j] = agent_pos[b * 6 + 2 * j];
            py[j] = agent_pos[b * 6 + 2 * j + 1];
        }
    } else {
#pragma unroll
        for (int m = 0; m < 3; ++m) {
            px[m] = lm_pos[b * 18 + 2 * m];
            py[m] = lm_pos[b * 18 + 2 * m + 1];
        }
    }

    // ---- xl = x@Wl+bl, xr = x@Wr+br, one node at a time to bound live regs ----
    float xl[3][16], xr[3][16];
#pragma unroll
    for (int j = 0; j < 3; ++j) {
        float xf[14];
        if (g == 0) {
            xf[0] = px[j]; xf[1] = py[j];
            xf[2] = agent_vel[b * 6 + 2 * j];
            xf[3] = agent_vel[b * 6 + 2 * j + 1];
#pragma unroll
            for (int k = 0; k < 6; ++k) xf[4 + k] = rel_lm[b * 18 + j * 6 + k];
#pragma unroll
            for (int k = 0; k < 4; ++k) xf[10 + k] = other_pos[b * 12 + j * 4 + k];
        } else {
            xf[0] = px[j]; xf[1] = py[j];
            xf[2] = 0.f;   xf[3] = 0.f;
#pragma unroll
            for (int m = 0; m < 3; ++m) {
                xf[4 + 2 * m] = px[m] - px[j];
                xf[5 + 2 * m] = py[m] - py[j];
            }
            const int a = o0[j], c2 = o1[j];
            xf[10] = px[a]  - px[j]; xf[11] = py[a]  - py[j];
            xf[12] = px[c2] - px[j]; xf[13] = py[c2] - py[j];
        }
#pragma unroll
        for (int c = 0; c < 16; ++c) { xl[j][c] = bl[c]; xr[j][c] = br[c]; }
#pragma unroll
        for (int k = 0; k < 14; ++k) {
#pragma unroll
            for (int c = 0; c < 16; ++c) {
                xl[j][c] = fmaf(xf[k], Wl[k * 16 + c], xl[j][c]);
                xr[j][c] = fmaf(xf[k], Wr[k * 16 + c], xr[j][c]);
            }
        }
    }

    // ---- pairwise distances ----
    float dE[3][3];
    {
        float dx, dy, sq;
        dx = px[0] - px[1]; dy = py[0] - py[1]; sq = dx * dx + dy * dy;
        dE[0][1] = dE[1][0] = sq > 0.f ? sqrtf(sq) : 0.f;
        dx = px[0] - px[2]; dy = py[0] - py[2]; sq = dx * dx + dy * dy;
        dE[0][2] = dE[2][0] = sq > 0.f ? sqrtf(sq) : 0.f;
        dx = px[1] - px[2]; dy = py[1] - py[2]; sq = dx * dx + dy * dy;
        dE[1][2] = dE[2][1] = sq > 0.f ? sqrtf(sq) : 0.f;
    }

    // ---- logits[j][i] = att . leaky(xl[j] + xr[i] + attr[j][i] @ We) ----
    float lg[3][3];
#pragma unroll
    for (int i = 0; i < 3; ++i) {
#pragma unroll
        for (int j = 0; j < 3; ++j) {
            float axv, ayv, adv;
            if (i == j) {
                const int a = o0[i], c2 = o1[i];
                axv = 0.5f * (px[a] + px[c2]) - px[i];
                ayv = 0.5f * (py[a] + py[c2]) - py[i];
                adv = 0.5f * (dE[a][i] + dE[c2][i]);
            } else {
                axv = px[j] - px[i];
                ayv = py[j] - py[i];
                adv = dE[j][i];
            }
            float acc = 0.f;
#pragma unroll
            for (int c = 0; c < 16; ++c) {
                float gg = xl[j][c] + xr[i][c];
                gg = fmaf(axv, We[c], gg);
                gg = fmaf(ayv, We[16 + c], gg);
                gg = fmaf(adv, We[32 + c], gg);
                acc = fmaf(leaky(gg), att[c], acc);
            }
            lg[j][i] = acc;
        }
    }

    // ---- softmax over j per target i; pooled hs[c] = sum_i relu(out_i[c]) ----
    float hs[16];
#pragma unroll
    for (int c = 0; c < 16; ++c) hs[c] = 0.f;
#pragma unroll
    for (int i = 0; i < 3; ++i) {
        float m = fmaxf(lg[0][i], fmaxf(lg[1][i], lg[2][i]));
        float e0 = __expf(lg[0][i] - m);
        float e1 = __expf(lg[1][i] - m);
        float e2 = __expf(lg[2][i] - m);
        float inv = 1.f / (e0 + e1 + e2);
        float a0 = e0 * inv, a1 = e1 * inv, a2 = e2 * inv;
#pragma unroll
        for (int c = 0; c < 16; ++c) {
            float v = fmaf(a0, xl[0][c], fmaf(a1, xl[1][c], fmaf(a2, xl[2][c], bias[c])));
            hs[c] += relu_f(v);
        }
    }

    // ---- exchange pooled halves through LDS: h[0..15]=agent(g0), h[16..31]=objective(g1) ----
    __syncthreads();
#pragma unroll
    for (int c = 0; c < 16; ++c) lds[pair * 33 + g * 16 + c] = hs[c];
    __syncthreads();

    const int s    = tid & 127;
    const int half = tid >> 7;         // wave-uniform -> weight indices stay scalar
    float h[32];
#pragma unroll
    for (int k = 0; k < 32; ++k) h[k] = lds[s * 33 + k];
    __syncthreads();                   // all reads done before o-partial overwrite

    // ---- MLP: this thread does hidden units [half*64, half*64+64) ----
    float o[32];
#pragma unroll
    for (int c = 0; c < 32; ++c) o[c] = 0.f;

#pragma unroll
    for (int hc = 0; hc < 4; ++hc) {
        const int base = half * 64 + hc * 16;
        float z[16];
#pragma unroll
        for (int u = 0; u < 16; ++u) z[u] = b1[base + u];
#pragma unroll
        for (int k = 0; k < 32; ++k) {
#pragma unroll
            for (int u = 0; u < 16; ++u)
                z[u] = fmaf(h[k], W1[k * 128 + base + u], z[u]);
        }
#pragma unroll
        for (int u = 0; u < 16; ++u) {
            float zz = relu_f(z[u]);
#pragma unroll
            for (int c = 0; c < 32; ++c)
                o[c] = fmaf(zz, W2[(base + u) * 32 + c], o[c]);
        }
    }

    // ---- combine halves: half1 writes partials, half0 adds + stores ----
    if (half == 1) {
#pragma unroll
        for (int c = 0; c < 32; ++c) lds[s * 33 + c] = o[c];
    }
    __syncthreads();
    if (half == 0) {
        const int bS = blockIdx.x * 128 + s;
        if (bS < Btot) {
#pragma unroll
            for (int c = 0; c < 32; ++c) o[c] += lds[s * 33 + c] + b2[c];
#pragma unroll
            for (int q = 0; q < 8; ++q) {
                float4 v = make_float4(o[q * 4 + 0], o[q * 4 + 1], o[q * 4 + 2], o[q * 4 + 3]);
                reinterpret_cast<float4*>(out)[bS * 8 + q] = v;
            }
        }
    }
}

extern "C" void kernel_launch(void* const* d_in, const int* in_sizes, int n_in,
                              void* d_out, int out_size, void* d_ws, size_t ws_size,
                              hipStream_t stream) {
    const float* agent_pos = (const float*)d_in[0];
    const float* agent_vel = (const float*)d_in[1];
    const float* rel_lm    = (const float*)d_in[2];
    const float* other_pos = (const float*)d_in[3];
    const float* lm_pos    = (const float*)d_in[4];
    const float* Wl   = (const float*)d_in[5];
    const float* bl   = (const float*)d_in[6];
    const float* Wr   = (const float*)d_in[7];
    const float* br   = (const float*)d_in[8];
    const float* We   = (const float*)d_in[9];
    const float* att  = (const float*)d_in[10];
    const float* bias = (const float*)d_in[11];
    const float* W1   = (const float*)d_in[12];
    const float* b1   = (const float*)d_in[13];
    const float* W2   = (const float*)d_in[14];
    const float* b2   = (const float*)d_in[15];
    float* out = (float*)d_out;

    int B = in_sizes[0] / 6;                  // agent_pos is [B,3,2]
    int samplesPerBlock = 128;
    int grid = (B + samplesPerBlock - 1) / samplesPerBlock;
    scl_fused_kernel<<<grid, 256, 0, stream>>>(
        agent_pos, agent_vel, rel_lm, other_pos, lm_pos,
        Wl, bl, Wr, br, We, att, bias, W1, b1, W2, b2, out, B);
}